// Round 9
// baseline (680.688 us; speedup 1.0000x reference)
//
#include <hip/hip_runtime.h>
#include <hip/hip_bf16.h>
#include <cstdint>

typedef __bf16 bf16_t;
typedef __bf16 bf16x8 __attribute__((ext_vector_type(8)));
typedef float f32x4 __attribute__((ext_vector_type(4)));

#define DEV_INLINE __device__ __forceinline__

#define NTOK 8192
#define DDIM 1024
#define HDIM 4096
#define SDIM 1024
#define NEXP 8
#define HEXP 512
#define TSEQ 2048
#define MAXTILES 136
#define MAXROWS (MAXTILES * 128)

#define VMCNT(n) asm volatile("s_waitcnt vmcnt(" #n ")" ::: "memory")
#define BARF() asm volatile("s_barrier" ::: "memory")

// ---------------- conversion: f32 -> bf16, 8 elems/thread ----------------
__global__ __launch_bounds__(256) void k_f32_to_bf16(const float* __restrict__ src,
                                                     bf16_t* __restrict__ dst, int n8) {
  int i = blockIdx.x * 256 + threadIdx.x;
  if (i >= n8) return;
  const float4* s = (const float4*)src + (size_t)i * 2;
  float4 v0 = s[0], v1 = s[1];
  bf16x8 o;
  o[0] = (bf16_t)v0.x; o[1] = (bf16_t)v0.y; o[2] = (bf16_t)v0.z; o[3] = (bf16_t)v0.w;
  o[4] = (bf16_t)v1.x; o[5] = (bf16_t)v1.y; o[6] = (bf16_t)v1.z; o[7] = (bf16_t)v1.w;
  *((bf16x8*)dst + i) = o;
}

// ------------- conv weight: [S][S][K] f32 -> [S][K*S] bf16 (k-major) -------------
__global__ __launch_bounds__(256) void k_convw(const float* __restrict__ src,
                                               bf16_t* __restrict__ dst) {
  int i = blockIdx.x * 256 + threadIdx.x;
  size_t flat = (size_t)i * 8;
  int s = (int)(flat >> 12);
  int col = (int)(flat & 4095);
  int k = col >> 10;
  int si0 = col & 1023;
  const float* sp = src + (size_t)s * 4096 + k;
  bf16x8 o;
#pragma unroll
  for (int j = 0; j < 8; ++j) o[j] = (bf16_t)sp[(size_t)(si0 + j) * 4];
  *(bf16x8*)(dst + flat) = o;
}

// ------------- im2col: h[8192][1024] -> A2[8192][4096] -------------
__global__ __launch_bounds__(256) void k_im2col(const bf16_t* __restrict__ h,
                                                bf16_t* __restrict__ a2) {
  int i = blockIdx.x * 256 + threadIdx.x;
  size_t flat = (size_t)i * 8;
  int t = (int)(flat >> 12);
  int col = (int)(flat & 4095);
  int k = col >> 10;
  int si = col & 1023;
  int tt = t & (TSEQ - 1);
  bf16x8 v;
#pragma unroll
  for (int j = 0; j < 8; ++j) v[j] = (bf16_t)0.f;
  if (tt - 3 + k >= 0) v = *(const bf16x8*)(h + (size_t)(t - 3 + k) * SDIM + si);
  *(bf16x8*)(a2 + flat) = v;
}

// ------------- MoE bookkeeping (round-8 proven, contention-free) -------------
__global__ __launch_bounds__(256) void k_zero(int* cnt, int* fill, int* idx,
                                              float* gate) {
  int i = blockIdx.x * 256 + threadIdx.x;
  if (i < NEXP) { cnt[i] = 0; fill[i] = 0; }
  if (i < MAXROWS) { idx[i] = 0; gate[i] = 0.f; }
}

__global__ __launch_bounds__(1024) void k_count(const int* __restrict__ top2e,
                                                int* __restrict__ cnt) {
  __shared__ int hist[NEXP];
  const int tid = threadIdx.x;
  if (tid < NEXP) hist[tid] = 0;
  __syncthreads();
  int c[NEXP];
#pragma unroll
  for (int e = 0; e < NEXP; ++e) c[e] = 0;
#pragma unroll
  for (int j = 0; j < 2 * NTOK / 1024; ++j) {
    int v = top2e[j * 1024 + tid];
#pragma unroll
    for (int e = 0; e < NEXP; ++e) c[e] += (v == e) ? 1 : 0;
  }
#pragma unroll
  for (int e = 0; e < NEXP; ++e)
    for (int off = 32; off; off >>= 1) c[e] += __shfl_xor(c[e], off);
  if ((tid & 63) == 0) {
#pragma unroll
    for (int e = 0; e < NEXP; ++e) atomicAdd(&hist[e], c[e]);
  }
  __syncthreads();
  if (tid < NEXP) cnt[tid] = hist[tid];
}

__global__ void k_scan(const int* __restrict__ cnt, int* __restrict__ base,
                       int* __restrict__ ntiles, int* __restrict__ tile_e,
                       int* __restrict__ tile_row) {
  if (threadIdx.x == 0 && blockIdx.x == 0) {
    int b = 0, tt = 0;
    for (int e = 0; e < NEXP; ++e) {
      base[e] = b;
      int nt = (cnt[e] + 127) >> 7;
      for (int j = 0; j < nt; ++j) { tile_e[tt] = e; tile_row[tt] = b + j * 128; ++tt; }
      b += nt * 128;
    }
    *ntiles = tt;
  }
}

__global__ __launch_bounds__(256) void k_scatter(const int* __restrict__ top2e,
                                                 const float* __restrict__ top2w,
                                                 const int* __restrict__ base,
                                                 int* __restrict__ fill,
                                                 int* __restrict__ idx,
                                                 float* __restrict__ gate) {
  __shared__ int lcnt[NEXP];
  __shared__ int lbase[NEXP];
  const int tid = threadIdx.x;
  const int t = blockIdx.x * 256 + tid;
  if (tid < NEXP) lcnt[tid] = 0;
  __syncthreads();
  const int e0 = top2e[t * 2 + 0], e1 = top2e[t * 2 + 1];
  const int s0 = atomicAdd(&lcnt[e0], 1);
  const int s1 = atomicAdd(&lcnt[e1], 1);
  __syncthreads();
  if (tid < NEXP) lbase[tid] = atomicAdd(&fill[tid], lcnt[tid]);
  __syncthreads();
  const int p0 = base[e0] + lbase[e0] + s0;
  const int p1 = base[e1] + lbase[e1] + s1;
  idx[p0] = t; gate[p0] = top2w[t * 2 + 0];
  idx[p1] = t; gate[p1] = top2w[t * 2 + 1];
}

// ------------- router (no atomics) -------------
__global__ __launch_bounds__(256) void k_router(const float* __restrict__ x,
                                                const float* __restrict__ rW,
                                                const float* __restrict__ rb,
                                                const float* __restrict__ mW,
                                                const float* __restrict__ mb,
                                                float* __restrict__ bw3,
                                                int* __restrict__ top2e,
                                                float* __restrict__ top2w) {
  int wave = threadIdx.x >> 6, lane = threadIdx.x & 63;
  int t = blockIdx.x * 4 + wave;
  const float* xr = x + (size_t)t * DDIM;
  float xv[16];
#pragma unroll
  for (int i = 0; i < 16; i += 4) *(float4*)&xv[i] = *(const float4*)&xr[lane * 16 + i];
  float acc[11];
#pragma unroll
  for (int j = 0; j < 11; ++j) {
    const float* w = (j < 3) ? (rW + j * DDIM) : (mW + (j - 3) * DDIM);
    float s = 0.f;
#pragma unroll
    for (int i = 0; i < 16; i += 4) {
      float4 wv = *(const float4*)&w[lane * 16 + i];
      s += xv[i] * wv.x + xv[i + 1] * wv.y + xv[i + 2] * wv.z + xv[i + 3] * wv.w;
    }
    acc[j] = s;
  }
#pragma unroll
  for (int j = 0; j < 11; ++j)
    for (int off = 32; off; off >>= 1) acc[j] += __shfl_xor(acc[j], off);
  if (lane == 0) {
    float l0 = acc[0] + rb[0], l1 = acc[1] + rb[1], l2 = acc[2] + rb[2];
    float mx = fmaxf(l0, fmaxf(l1, l2));
    float e0 = expf(l0 - mx), e1 = expf(l1 - mx), e2 = expf(l2 - mx);
    float inv = 1.f / (e0 + e1 + e2);
    float w2 = e2 * inv;
    bw3[t * 3 + 0] = e0 * inv; bw3[t * 3 + 1] = e1 * inv; bw3[t * 3 + 2] = w2;
    float lg[8];
#pragma unroll
    for (int e = 0; e < 8; ++e) lg[e] = acc[3 + e] + mb[e];
    int i0 = 0;
#pragma unroll
    for (int e = 1; e < 8; ++e) if (lg[e] > lg[i0]) i0 = e;
    int i1 = -1;
#pragma unroll
    for (int e = 0; e < 8; ++e) {
      if (e == i0) continue;
      if (i1 < 0 || lg[e] > lg[i1]) i1 = e;
    }
    float ee = expf(lg[i1] - lg[i0]);
    float w0 = 1.f / (1.f + ee), w1 = ee / (1.f + ee);
    top2e[t * 2 + 0] = i0; top2e[t * 2 + 1] = i1;
    top2w[t * 2 + 0] = w2 * w0; top2w[t * 2 + 1] = w2 * w1;
  }
}

// =======================================================================
// m97-style GEMM core: 128x128 tile, 256 thr = 4 waves (2x2, 64x64 each),
// BK=32, double-buffered 32 KB LDS -> ~4 blocks/CU co-resident (cross-
// block overlap hides the vmcnt(0)+barrier drain, m114 regime). Conflict-
// free LDS: rows=64B (4x16B slots), slot' = hi ^ ((row>>1)&3), applied as
// pre-swizzled GLOBAL source + same XOR on ds_read (gload_lds dest linear).
// =======================================================================
DEV_INLINE void gload16(const bf16_t* g, bf16_t* l) {
  __builtin_amdgcn_global_load_lds((const __attribute__((address_space(1))) void*)g,
                                   (__attribute__((address_space(3))) void*)l, 16, 0, 0);
}

constexpr int EPI_BF16 = 0;   // Cb = bf16(v + bias[col])
constexpr int EPI_OUT_W = 1;  // Cf = scale[row]*(v+bias)
constexpr int EPI_OUT_A = 2;  // Cf += scale[row]*(v+bias)
constexpr int EPI_SWIG = 4;   // Cb = bf16(silu(v+bias)*aux[row,col])
constexpr int EPI_SCAT = 5;   // atomicAdd(Cf[token], gate*(v+bias)) [MoE fc2]

template <int EPI>
__global__ __launch_bounds__(256) void k_gemm(
    const bf16_t* __restrict__ A, const bf16_t* __restrict__ B,
    bf16_t* __restrict__ Cb, float* __restrict__ Cf,
    const float* __restrict__ bias, const float* __restrict__ scale, int sstride,
    const bf16_t* __restrict__ aux, int ldaux,
    int N, int K) {
  constexpr int BUF = 16384;  // 8 KB A + 8 KB B per buffer
  __shared__ __align__(16) char lds[2 * BUF];

  const int tid = threadIdx.x;
  const int lane = tid & 63;
  const int wave = tid >> 6;
  const int lr = lane & 15;
  const int hi = lane >> 4;

  // bijective XCD-aware swizzle (all grids %8==0)
  const int nbx = gridDim.x, nby = gridDim.y;
  int id = blockIdx.x + nbx * blockIdx.y;
  const int nwg = nbx * nby;
  if ((nwg & 7) == 0) id = (id & 7) * (nwg >> 3) + (id >> 3);
  const int bx = id % nbx;
  const int by = id / nbx;

  const int bm = by * 128;
  const int bn = bx * 128;
  const int wm = (wave >> 1) * 64;
  const int wn = (wave & 1) * 64;

  // staging: slot s (16B) of a region holds G[row=s>>2][8*((s&3)^((row>>1)&3)) ..+8)
  const int srow = tid >> 2;                       // 0..63 (pass 1)
  const int scol = 8 * ((tid & 3) ^ ((tid >> 3) & 3));
  const bf16_t* Asrc = A + (size_t)(bm + srow) * K + scol;
  const bf16_t* Bsrc = B + (size_t)(bn + srow) * K + scol;
  const size_t r64K = (size_t)64 * K;
  const int NT = K >> 5;

  f32x4 acc[4][4];
#pragma unroll
  for (int a = 0; a < 4; ++a)
#pragma unroll
    for (int b = 0; b < 4; ++b)
#pragma unroll
      for (int j = 0; j < 4; ++j) acc[a][b][j] = 0.f;

  auto stage = [&](int t) {
    char* l = lds + (t & 1) * BUF + tid * 16;
    const bf16_t* ga = Asrc + (size_t)t * 32;
    const bf16_t* gb = Bsrc + (size_t)t * 32;
    gload16(ga, (bf16_t*)l);                      // A rows 0..63
    gload16(ga + r64K, (bf16_t*)(l + 4096));      // A rows 64..127
    gload16(gb, (bf16_t*)(l + 8192));             // B rows 0..63
    gload16(gb + r64K, (bf16_t*)(l + 12288));     // B rows 64..127
  };
  auto rdA = [&](int buf, int row) -> bf16x8 {
    int off = buf + (row << 6) + ((hi ^ ((row >> 1) & 3)) << 4);
    return *(const bf16x8*)(lds + off);
  };
  auto rdB = [&](int buf, int row) -> bf16x8 {
    int off = buf + 8192 + (row << 6) + ((hi ^ ((row >> 1) & 3)) << 4);
    return *(const bf16x8*)(lds + off);
  };

  stage(0);

  for (int t = 0; t < NT; ++t) {
    VMCNT(0);
    BARF();
    const int buf = (t & 1) * BUF;
    bf16x8 bfr[4], afr[4];
#pragma unroll
    for (int ni = 0; ni < 4; ++ni) bfr[ni] = rdB(buf, wn + ni * 16 + lr);
#pragma unroll
    for (int i = 0; i < 4; ++i) afr[i] = rdA(buf, wm + i * 16 + lr);
    if (t + 1 < NT) stage(t + 1);
    __builtin_amdgcn_s_setprio(1);
#pragma unroll
    for (int i = 0; i < 4; ++i)
#pragma unroll
      for (int ni = 0; ni < 4; ++ni)
        acc[i][ni] = __builtin_amdgcn_mfma_f32_16x16x32_bf16(afr[i], bfr[ni], acc[i][ni], 0, 0, 0);
    __builtin_amdgcn_s_setprio(0);
  }

  // ---------------- epilogue ----------------
  float bv[4];
#pragma unroll
  for (int ni = 0; ni < 4; ++ni) bv[ni] = bias[bn + wn + ni * 16 + lr];
#pragma unroll
  for (int mi = 0; mi < 4; ++mi) {
#pragma unroll
    for (int j = 0; j < 4; ++j) {
      const int rowg = bm + wm + mi * 16 + hi * 4 + j;
      float sc = 0.f;
      if constexpr (EPI == EPI_OUT_W || EPI == EPI_OUT_A)
        sc = scale[(size_t)rowg * sstride];
#pragma unroll
      for (int ni = 0; ni < 4; ++ni) {
        const int colg = bn + wn + ni * 16 + lr;
        float v = acc[mi][ni][j] + bv[ni];
        if constexpr (EPI == EPI_BF16) {
          Cb[(size_t)rowg * N + colg] = (bf16_t)v;
        } else if constexpr (EPI == EPI_OUT_W) {
          Cf[(size_t)rowg * N + colg] = sc * v;
        } else if constexpr (EPI == EPI_OUT_A) {
          Cf[(size_t)rowg * N + colg] += sc * v;
        } else {
          float bb = (float)aux[(size_t)rowg * ldaux + colg];
          float s = v / (1.f + __expf(-v));
          Cb[(size_t)rowg * N + colg] = (bf16_t)(s * bb);
        }
      }
    }
  }
}

// =======================================================================
// Sparse MoE GEMM: same 128x128 4-wave core; A rows gathered via idx[]
// (GA, fc1) or slot-linear (fc2); EPI_SCAT scatters to out[token] with
// per-slot gate via atomicAdd.
// =======================================================================
template <int EPI, bool GA>
__global__ __launch_bounds__(256) void k_moe_gemm(
    const bf16_t* __restrict__ A, const bf16_t* __restrict__ Bw, size_t zB, int boff,
    bf16_t* __restrict__ Cb, float* __restrict__ Cf,
    const float* __restrict__ bias, int bstride,
    const bf16_t* __restrict__ aux,
    const int* __restrict__ ntiles_p, const int* __restrict__ tile_e,
    const int* __restrict__ tile_row, const int* __restrict__ idx,
    const float* __restrict__ gate,
    int N, int K) {
  constexpr int BUF = 16384;
  __shared__ __align__(16) char lds[2 * BUF];

  const int tid = threadIdx.x;
  const int lane = tid & 63;
  const int wave = tid >> 6;
  const int lr = lane & 15;
  const int hi = lane >> 4;

  const int nbx = gridDim.x, nby = gridDim.y;
  int id = blockIdx.x + nbx * blockIdx.y;
  const int nwg = nbx * nby;
  if ((nwg & 7) == 0) id = (id & 7) * (nwg >> 3) + (id >> 3);
  const int bx = id % nbx;
  const int by = id / nbx;

  const int ntiles = *ntiles_p;
  if (bx >= ntiles) return;
  const int e = tile_e[bx];
  const int bm = tile_row[bx];
  const int bn = by * 128;
  const int wm = (wave >> 1) * 64;
  const int wn = (wave & 1) * 64;

  const int srow = tid >> 2;
  const int scol = 8 * ((tid & 3) ^ ((tid >> 3) & 3));
  const int atok0 = GA ? idx[bm + srow] : (bm + srow);
  const int atok1 = GA ? idx[bm + srow + 64] : (bm + srow + 64);
  const bf16_t* Asrc0 = A + (size_t)atok0 * K + scol;
  const bf16_t* Asrc1 = A + (size_t)atok1 * K + scol;
  const bf16_t* Bsrc = Bw + (size_t)e * zB + (size_t)(boff + bn + srow) * K + scol;
  const size_t r64K = (size_t)64 * K;
  const int NT = K >> 5;

  f32x4 acc[4][4];
#pragma unroll
  for (int a = 0; a < 4; ++a)
#pragma unroll
    for (int b = 0; b < 4; ++b)
#pragma unroll
      for (int j = 0; j < 4; ++j) acc[a][b][j] = 0.f;

  auto stage = [&](int t) {
    char* l = lds + (t & 1) * BUF + tid * 16;
    gload16(Asrc0 + (size_t)t * 32, (bf16_t*)l);
    gload16(Asrc1 + (size_t)t * 32, (bf16_t*)(l + 4096));
    gload16(Bsrc + (size_t)t * 32, (bf16_t*)(l + 8192));
    gload16(Bsrc + (size_t)t * 32 + r64K, (bf16_t*)(l + 12288));
  };
  auto rdA = [&](int buf, int row) -> bf16x8 {
    int off = buf + (row << 6) + ((hi ^ ((row >> 1) & 3)) << 4);
    return *(const bf16x8*)(lds + off);
  };
  auto rdB = [&](int buf, int row) -> bf16x8 {
    int off = buf + 8192 + (row << 6) + ((hi ^ ((row >> 1) & 3)) << 4);
    return *(const bf16x8*)(lds + off);
  };

  stage(0);

  for (int t = 0; t < NT; ++t) {
    VMCNT(0);
    BARF();
    const int buf = (t & 1) * BUF;
    bf16x8 bfr[4], afr[4];
#pragma unroll
    for (int ni = 0; ni < 4; ++ni) bfr[ni] = rdB(buf, wn + ni * 16 + lr);
#pragma unroll
    for (int i = 0; i < 4; ++i) afr[i] = rdA(buf, wm + i * 16 + lr);
    if (t + 1 < NT) stage(t + 1);
    __builtin_amdgcn_s_setprio(1);
#pragma unroll
    for (int i = 0; i < 4; ++i)
#pragma unroll
      for (int ni = 0; ni < 4; ++ni)
        acc[i][ni] = __builtin_amdgcn_mfma_f32_16x16x32_bf16(afr[i], bfr[ni], acc[i][ni], 0, 0, 0);
    __builtin_amdgcn_s_setprio(0);
  }

  const float* bp = bias + (size_t)e * bstride + boff;
  float bv[4];
#pragma unroll
  for (int ni = 0; ni < 4; ++ni) bv[ni] = bp[bn + wn + ni * 16 + lr];
#pragma unroll
  for (int mi = 0; mi < 4; ++mi) {
#pragma unroll
    for (int j = 0; j < 4; ++j) {
      const int slot = bm + wm + mi * 16 + hi * 4 + j;
      float sc = 0.f;
      int tok = 0;
      if constexpr (EPI == EPI_SCAT) { sc = gate[slot]; tok = idx[slot]; }
#pragma unroll
      for (int ni = 0; ni < 4; ++ni) {
        const int colg = bn + wn + ni * 16 + lr;
        float v = acc[mi][ni][j] + bv[ni];
        if constexpr (EPI == EPI_BF16) {
          Cb[(size_t)slot * N + colg] = (bf16_t)v;
        } else if constexpr (EPI == EPI_SWIG) {
          float bb = (float)aux[(size_t)slot * N + colg];
          float s = v / (1.f + __expf(-v));
          Cb[(size_t)slot * N + colg] = (bf16_t)(s * bb);
        } else {
          if (sc != 0.f) atomicAdd(&Cf[(size_t)tok * N + colg], sc * v);
        }
      }
    }
  }
}

// ---------------------------------------------------------------------------
extern "C" void kernel_launch(void* const* d_in, const int* in_sizes, int n_in,
                              void* d_out, int out_size, void* d_ws, size_t ws_size,
                              hipStream_t stream) {
  (void)in_sizes; (void)n_in; (void)out_size; (void)ws_size;
  const float* x    = (const float*)d_in[0];
  const float* rW   = (const float*)d_in[1];
  const float* rb   = (const float*)d_in[2];
  const float* d1W  = (const float*)d_in[3];
  const float* d1b  = (const float*)d_in[4];
  const float* d2W  = (const float*)d_in[5];
  const float* d2b  = (const float*)d_in[6];
  const float* sWin = (const float*)d_in[7];
  const float* sbin = (const float*)d_in[8];
  const float* sWc  = (const float*)d_in[9];
  const float* sbc  = (const float*)d_in[10];
  const float* sWo  = (const float*)d_in[11];
  const float* sbo  = (const float*)d_in[12];
  const float* mW   = (const float*)d_in[13];
  const float* mb   = (const float*)d_in[14];
  const float* eW1  = (const float*)d_in[15];
  const float* eb1  = (const float*)d_in[16];
  const float* eW2  = (const float*)d_in[17];
  const float* eb2  = (const float*)d_in[18];
  float* out = (float*)d_out;

  char* ws = (char*)d_ws;
  size_t off = 0;
  auto alloc = [&](size_t bytes) -> void* {
    void* p = ws + off;
    off += (bytes + 255) & ~(size_t)255;
    return p;
  };
  bf16_t* xb    = (bf16_t*)alloc((size_t)NTOK * DDIM * 2);
  bf16_t* wd1   = (bf16_t*)alloc((size_t)2 * HDIM * DDIM * 2);
  bf16_t* wd2   = (bf16_t*)alloc((size_t)DDIM * HDIM * 2);
  bf16_t* wsin  = (bf16_t*)alloc((size_t)SDIM * DDIM * 2);
  bf16_t* wconv = (bf16_t*)alloc((size_t)SDIM * SDIM * 4 * 2);
  bf16_t* wsout = (bf16_t*)alloc((size_t)DDIM * SDIM * 2);
  bf16_t* we1   = (bf16_t*)alloc((size_t)NEXP * 2 * HEXP * DDIM * 2);
  bf16_t* we2   = (bf16_t*)alloc((size_t)NEXP * DDIM * HEXP * 2);
  bf16_t* Cc    = (bf16_t*)alloc((size_t)NTOK * HDIM * 2);
  bf16_t* Dd    = (bf16_t*)alloc((size_t)NTOK * HDIM * 2);
  bf16_t* th    = (bf16_t*)alloc((size_t)NTOK * SDIM * 2);
  bf16_t* tsq   = (bf16_t*)alloc((size_t)NTOK * SDIM * 2);
  float*  bw3   = (float*)alloc((size_t)NTOK * 3 * 4);
  int*    top2e = (int*)alloc((size_t)NTOK * 2 * 4);
  float*  top2w = (float*)alloc((size_t)NTOK * 2 * 4);
  int*    cnt   = (int*)alloc(NEXP * 4);
  int*    fill  = (int*)alloc(NEXP * 4);
  int*    basep = (int*)alloc((NEXP + 1) * 4);
  int*    ntl   = (int*)alloc(4);
  int*    t_e   = (int*)alloc(MAXTILES * 4);
  int*    t_row = (int*)alloc(MAXTILES * 4);
  int*    idx   = (int*)alloc(MAXROWS * 4);
  float*  gate  = (float*)alloc(MAXROWS * 4);

  // conversions + router + MoE bookkeeping
  k_f32_to_bf16<<<4096, 256, 0, stream>>>(x, xb, NTOK * DDIM / 8);
  k_f32_to_bf16<<<4096, 256, 0, stream>>>(d1W, wd1, 2 * HDIM * DDIM / 8);
  k_f32_to_bf16<<<2048, 256, 0, stream>>>(d2W, wd2, DDIM * HDIM / 8);
  k_f32_to_bf16<<<512, 256, 0, stream>>>(sWin, wsin, SDIM * DDIM / 8);
  k_convw<<<2048, 256, 0, stream>>>(sWc, wconv);
  k_f32_to_bf16<<<512, 256, 0, stream>>>(sWo, wsout, DDIM * SDIM / 8);
  k_f32_to_bf16<<<4096, 256, 0, stream>>>(eW1, we1, NEXP * 2 * HEXP * DDIM / 8);
  k_f32_to_bf16<<<2048, 256, 0, stream>>>(eW2, we2, NEXP * DDIM * HEXP / 8);
  k_zero<<<(MAXROWS + 255) / 256, 256, 0, stream>>>(cnt, fill, idx, gate);
  k_router<<<2048, 256, 0, stream>>>(x, rW, rb, mW, mb, bw3, top2e, top2w);
  k_count<<<1, 1024, 0, stream>>>(top2e, cnt);
  k_scan<<<1, 64, 0, stream>>>(cnt, basep, ntl, t_e, t_row);
  k_scatter<<<NTOK / 256, 256, 0, stream>>>(top2e, top2w, basep, fill, idx, gate);

  // ---- dense branch: fc1-b, fc1-a(+fused swiglu), d2 -> out ----
  k_gemm<EPI_BF16><<<dim3(32, 64), 256, 0, stream>>>(
      xb, wd1 + (size_t)HDIM * DDIM, Dd, nullptr, d1b + HDIM, nullptr, 0, nullptr, 0,
      HDIM, DDIM);
  k_gemm<EPI_SWIG><<<dim3(32, 64), 256, 0, stream>>>(
      xb, wd1, Cc, nullptr, d1b, nullptr, 0, Dd, HDIM, HDIM, DDIM);
  k_gemm<EPI_OUT_W><<<dim3(8, 64), 256, 0, stream>>>(
      Cc, wd2, nullptr, out, d2b, bw3, 3, nullptr, 0, DDIM, HDIM);

  // ---- sparse MoE: gathered fc1-b, fc1-a(+swiglu), fc2 scatter ----
  k_moe_gemm<EPI_BF16, true><<<dim3(MAXTILES, 4), 256, 0, stream>>>(
      xb, we1, (size_t)2 * HEXP * DDIM, HEXP, Dd, nullptr, eb1, 2 * HEXP, nullptr,
      ntl, t_e, t_row, idx, gate, HEXP, DDIM);
  k_moe_gemm<EPI_SWIG, true><<<dim3(MAXTILES, 4), 256, 0, stream>>>(
      xb, we1, (size_t)2 * HEXP * DDIM, 0, Cc, nullptr, eb1, 2 * HEXP, Dd,
      ntl, t_e, t_row, idx, gate, HEXP, DDIM);
  k_moe_gemm<EPI_SCAT, false><<<dim3(MAXTILES, 8), 256, 0, stream>>>(
      Cc, we2, (size_t)DDIM * HEXP, 0, nullptr, out, eb2, DDIM, nullptr,
      ntl, t_e, t_row, idx, gate, DDIM, HEXP);

  // ---- SSM branch ----
  k_gemm<EPI_BF16><<<dim3(8, 64), 256, 0, stream>>>(
      xb, wsin, th, nullptr, sbin, nullptr, 0, nullptr, 0, SDIM, DDIM);
  k_im2col<<<16384, 256, 0, stream>>>(th, Dd);
  k_gemm<EPI_BF16><<<dim3(8, 64), 256, 0, stream>>>(
      Dd, wconv, tsq, nullptr, sbc, nullptr, 0, nullptr, 0, SDIM, SDIM * 4);
  k_gemm<EPI_OUT_A><<<dim3(8, 64), 256, 0, stream>>>(
      tsq, wsout, nullptr, out, sbo, bw3 + 1, 3, nullptr, 0, DDIM, SDIM);
}

// Round 11
// 669.888 us; speedup vs baseline: 1.0161x; 1.0161x over previous
//
#include <hip/hip_runtime.h>
#include <hip/hip_bf16.h>
#include <cstdint>

typedef __bf16 bf16_t;
typedef __bf16 bf16x8 __attribute__((ext_vector_type(8)));
typedef float f32x4 __attribute__((ext_vector_type(4)));

#define DEV_INLINE __device__ __forceinline__

#define NTOK 8192
#define DDIM 1024
#define HDIM 4096
#define SDIM 1024
#define NEXP 8
#define HEXP 512
#define TSEQ 2048
#define MAXTILES 136
#define MAXROWS (MAXTILES * 128)

#define VMCNT(n) asm volatile("s_waitcnt vmcnt(" #n ")" ::: "memory")
#define BARF() asm volatile("s_barrier" ::: "memory")

// ---------------- conversion: f32 -> bf16, 8 elems/thread ----------------
__global__ __launch_bounds__(256) void k_f32_to_bf16(const float* __restrict__ src,
                                                     bf16_t* __restrict__ dst, int n8) {
  int i = blockIdx.x * 256 + threadIdx.x;
  if (i >= n8) return;
  const float4* s = (const float4*)src + (size_t)i * 2;
  float4 v0 = s[0], v1 = s[1];
  bf16x8 o;
  o[0] = (bf16_t)v0.x; o[1] = (bf16_t)v0.y; o[2] = (bf16_t)v0.z; o[3] = (bf16_t)v0.w;
  o[4] = (bf16_t)v1.x; o[5] = (bf16_t)v1.y; o[6] = (bf16_t)v1.z; o[7] = (bf16_t)v1.w;
  *((bf16x8*)dst + i) = o;
}

// ------------- conv weight: [S][S][K] f32 -> [S][K*S] bf16 (k-major) -------------
__global__ __launch_bounds__(256) void k_convw(const float* __restrict__ src,
                                               bf16_t* __restrict__ dst) {
  int i = blockIdx.x * 256 + threadIdx.x;
  size_t flat = (size_t)i * 8;
  int s = (int)(flat >> 12);
  int col = (int)(flat & 4095);
  int k = col >> 10;
  int si0 = col & 1023;
  const float* sp = src + (size_t)s * 4096 + k;
  bf16x8 o;
#pragma unroll
  for (int j = 0; j < 8; ++j) o[j] = (bf16_t)sp[(size_t)(si0 + j) * 4];
  *(bf16x8*)(dst + flat) = o;
}

// ------------- MoE bookkeeping (contention-free) -------------
__global__ __launch_bounds__(256) void k_zero(int* cnt, int* fill, int* idx,
                                              bf16_t* zpad) {
  int i = blockIdx.x * 256 + threadIdx.x;
  if (i < NEXP) { cnt[i] = 0; fill[i] = 0; }
  if (i < 128) zpad[i] = (bf16_t)0.f;
  if (i < MAXROWS) idx[i] = 0;
}

__global__ __launch_bounds__(1024) void k_count(const int* __restrict__ top2e,
                                                int* __restrict__ cnt) {
  __shared__ int hist[NEXP];
  const int tid = threadIdx.x;
  if (tid < NEXP) hist[tid] = 0;
  __syncthreads();
  int c[NEXP];
#pragma unroll
  for (int e = 0; e < NEXP; ++e) c[e] = 0;
#pragma unroll
  for (int j = 0; j < 2 * NTOK / 1024; ++j) {
    int v = top2e[j * 1024 + tid];
#pragma unroll
    for (int e = 0; e < NEXP; ++e) c[e] += (v == e) ? 1 : 0;
  }
#pragma unroll
  for (int e = 0; e < NEXP; ++e)
    for (int off = 32; off; off >>= 1) c[e] += __shfl_xor(c[e], off);
  if ((tid & 63) == 0) {
#pragma unroll
    for (int e = 0; e < NEXP; ++e) atomicAdd(&hist[e], c[e]);
  }
  __syncthreads();
  if (tid < NEXP) cnt[tid] = hist[tid];
}

__global__ void k_scan(const int* __restrict__ cnt, int* __restrict__ base,
                       int* __restrict__ ntiles, int* __restrict__ tile_e,
                       int* __restrict__ tile_row) {
  if (threadIdx.x == 0 && blockIdx.x == 0) {
    int b = 0, tt = 0;
    for (int e = 0; e < NEXP; ++e) {
      base[e] = b;
      int nt = (cnt[e] + 127) >> 7;
      for (int j = 0; j < nt; ++j) { tile_e[tt] = e; tile_row[tt] = b + j * 128; ++tt; }
      b += nt * 128;
    }
    *ntiles = tt;
  }
}

// two-level scatter; also records the inverse map slotmap[token][2]
__global__ __launch_bounds__(256) void k_scatter(const int* __restrict__ top2e,
                                                 const float* __restrict__ top2w,
                                                 const int* __restrict__ base,
                                                 int* __restrict__ fill,
                                                 int* __restrict__ idx,
                                                 int* __restrict__ slotmap) {
  __shared__ int lcnt[NEXP];
  __shared__ int lbase[NEXP];
  const int tid = threadIdx.x;
  const int t = blockIdx.x * 256 + tid;
  if (tid < NEXP) lcnt[tid] = 0;
  __syncthreads();
  const int e0 = top2e[t * 2 + 0], e1 = top2e[t * 2 + 1];
  const int s0 = atomicAdd(&lcnt[e0], 1);
  const int s1 = atomicAdd(&lcnt[e1], 1);
  __syncthreads();
  if (tid < NEXP) lbase[tid] = atomicAdd(&fill[tid], lcnt[tid]);
  __syncthreads();
  const int p0 = base[e0] + lbase[e0] + s0;
  const int p1 = base[e1] + lbase[e1] + s1;
  idx[p0] = t; idx[p1] = t;
  slotmap[t * 2 + 0] = p0;
  slotmap[t * 2 + 1] = p1;
}

// ------------- router (no atomics) -------------
__global__ __launch_bounds__(256) void k_router(const float* __restrict__ x,
                                                const float* __restrict__ rW,
                                                const float* __restrict__ rb,
                                                const float* __restrict__ mW,
                                                const float* __restrict__ mb,
                                                float* __restrict__ bw3,
                                                int* __restrict__ top2e,
                                                float* __restrict__ top2w) {
  int wave = threadIdx.x >> 6, lane = threadIdx.x & 63;
  int t = blockIdx.x * 4 + wave;
  const float* xr = x + (size_t)t * DDIM;
  float xv[16];
#pragma unroll
  for (int i = 0; i < 16; i += 4) *(float4*)&xv[i] = *(const float4*)&xr[lane * 16 + i];
  float acc[11];
#pragma unroll
  for (int j = 0; j < 11; ++j) {
    const float* w = (j < 3) ? (rW + j * DDIM) : (mW + (j - 3) * DDIM);
    float s = 0.f;
#pragma unroll
    for (int i = 0; i < 16; i += 4) {
      float4 wv = *(const float4*)&w[lane * 16 + i];
      s += xv[i] * wv.x + xv[i + 1] * wv.y + xv[i + 2] * wv.z + xv[i + 3] * wv.w;
    }
    acc[j] = s;
  }
#pragma unroll
  for (int j = 0; j < 11; ++j)
    for (int off = 32; off; off >>= 1) acc[j] += __shfl_xor(acc[j], off);
  if (lane == 0) {
    float l0 = acc[0] + rb[0], l1 = acc[1] + rb[1], l2 = acc[2] + rb[2];
    float mx = fmaxf(l0, fmaxf(l1, l2));
    float e0 = expf(l0 - mx), e1 = expf(l1 - mx), e2 = expf(l2 - mx);
    float inv = 1.f / (e0 + e1 + e2);
    float w2 = e2 * inv;
    bw3[t * 3 + 0] = e0 * inv; bw3[t * 3 + 1] = e1 * inv; bw3[t * 3 + 2] = w2;
    float lg[8];
#pragma unroll
    for (int e = 0; e < 8; ++e) lg[e] = acc[3 + e] + mb[e];
    int i0 = 0;
#pragma unroll
    for (int e = 1; e < 8; ++e) if (lg[e] > lg[i0]) i0 = e;
    int i1 = -1;
#pragma unroll
    for (int e = 0; e < 8; ++e) {
      if (e == i0) continue;
      if (i1 < 0 || lg[e] > lg[i1]) i1 = e;
    }
    float ee = expf(lg[i1] - lg[i0]);
    float w0 = 1.f / (1.f + ee), w1 = ee / (1.f + ee);
    top2e[t * 2 + 0] = i0; top2e[t * 2 + 1] = i1;
    top2w[t * 2 + 0] = w2 * w0; top2w[t * 2 + 1] = w2 * w1;
  }
}

// ------------- MoE combine: out[t] += g0*eo[s0] + g1*eo[s1] (one wave/token) -------------
__global__ __launch_bounds__(256) void k_combine(const bf16_t* __restrict__ eo,
                                                 const int* __restrict__ slotmap,
                                                 const float* __restrict__ top2w,
                                                 float* __restrict__ out) {
  int wave = threadIdx.x >> 6, lane = threadIdx.x & 63;
  int t = blockIdx.x * 4 + wave;
  const int s0 = slotmap[t * 2 + 0], s1 = slotmap[t * 2 + 1];
  const float g0 = top2w[t * 2 + 0], g1 = top2w[t * 2 + 1];
  const bf16x8* r0 = (const bf16x8*)(eo + (size_t)s0 * DDIM);
  const bf16x8* r1 = (const bf16x8*)(eo + (size_t)s1 * DDIM);
  float* orow = out + (size_t)t * DDIM;
#pragma unroll
  for (int i = 0; i < 2; ++i) {
    const int d = lane + i * 64;           // bf16x8 index, 128 per row
    bf16x8 a = r0[d], b = r1[d];
    float vo[8];
    *(float4*)&vo[0] = *(const float4*)&orow[d * 8];
    *(float4*)&vo[4] = *(const float4*)&orow[d * 8 + 4];
#pragma unroll
    for (int j = 0; j < 8; ++j) vo[j] += g0 * (float)a[j] + g1 * (float)b[j];
    *(float4*)&orow[d * 8] = *(float4*)&vo[0];
    *(float4*)&orow[d * 8 + 4] = *(float4*)&vo[4];
  }
}

// =======================================================================
// m97-style GEMM core: 128x128 tile, 256 thr = 4 waves (2x2), BK=32,
// double-buffered 32 KB LDS. Conflict-free swizzle slot' = hi^((row>>1)&3)
// (pre-swizzled global source + XOR on ds_read). XCD chunking + (for
// K<=2048) a 4bx x 8by supertile remap so each XCD chunk's working set
// (~3 MB) fits its 4 MB L2 -> fewer L2 misses exposed in the vmcnt drain.
// =======================================================================
DEV_INLINE void gload16(const bf16_t* g, bf16_t* l) {
  __builtin_amdgcn_global_load_lds((const __attribute__((address_space(1))) void*)g,
                                   (__attribute__((address_space(3))) void*)l, 16, 0, 0);
}

DEV_INLINE void blockmap(int K, int& bx, int& by) {
  const int nbx = gridDim.x, nby = gridDim.y;
  int id = blockIdx.x + nbx * blockIdx.y;
  const int nwg = nbx * nby;
  if ((nwg & 7) == 0) id = (id & 7) * (nwg >> 3) + (id >> 3);
  if ((nbx & 3) == 0 && (nby & 7) == 0 && K <= 2048) {
    const int nsx = nbx >> 2;
    const int sx = id & 3, r = id >> 2;
    const int sy = r & 7, st = r >> 3;
    bx = (st % nsx) * 4 + sx;
    by = (st / nsx) * 8 + sy;
  } else {
    bx = id % nbx;
    by = id / nbx;
  }
}

constexpr int EPI_BF16 = 0;   // Cb = bf16(v + bias[col])
constexpr int EPI_OUT_W = 1;  // Cf = scale[row]*(v+bias)
constexpr int EPI_OUT_A = 2;  // Cf += scale[row]*(v+bias)
constexpr int EPI_SWIG = 4;   // Cb = bf16(silu(v+bias)*aux[row,col])

template <int EPI>
__global__ __launch_bounds__(256) void k_gemm(
    const bf16_t* __restrict__ A, const bf16_t* __restrict__ B,
    bf16_t* __restrict__ Cb, float* __restrict__ Cf,
    const float* __restrict__ bias, const float* __restrict__ scale, int sstride,
    const bf16_t* __restrict__ aux, int ldaux,
    int N, int K) {
  constexpr int BUF = 16384;
  __shared__ __align__(16) char lds[2 * BUF];

  const int tid = threadIdx.x;
  const int lane = tid & 63;
  const int wave = tid >> 6;
  const int lr = lane & 15;
  const int hi = lane >> 4;

  int bx, by;
  blockmap(K, bx, by);

  const int bm = by * 128;
  const int bn = bx * 128;
  const int wm = (wave >> 1) * 64;
  const int wn = (wave & 1) * 64;

  const int srow = tid >> 2;
  const int scol = 8 * ((tid & 3) ^ ((tid >> 3) & 3));
  const bf16_t* Asrc = A + (size_t)(bm + srow) * K + scol;
  const bf16_t* Bsrc = B + (size_t)(bn + srow) * K + scol;
  const size_t r64K = (size_t)64 * K;
  const int NT = K >> 5;

  f32x4 acc[4][4];
#pragma unroll
  for (int a = 0; a < 4; ++a)
#pragma unroll
    for (int b = 0; b < 4; ++b)
#pragma unroll
      for (int j = 0; j < 4; ++j) acc[a][b][j] = 0.f;

  auto stage = [&](int t) {
    char* l = lds + (t & 1) * BUF + tid * 16;
    const bf16_t* ga = Asrc + (size_t)t * 32;
    const bf16_t* gb = Bsrc + (size_t)t * 32;
    gload16(ga, (bf16_t*)l);
    gload16(ga + r64K, (bf16_t*)(l + 4096));
    gload16(gb, (bf16_t*)(l + 8192));
    gload16(gb + r64K, (bf16_t*)(l + 12288));
  };
  auto rdA = [&](int buf, int row) -> bf16x8 {
    int off = buf + (row << 6) + ((hi ^ ((row >> 1) & 3)) << 4);
    return *(const bf16x8*)(lds + off);
  };
  auto rdB = [&](int buf, int row) -> bf16x8 {
    int off = buf + 8192 + (row << 6) + ((hi ^ ((row >> 1) & 3)) << 4);
    return *(const bf16x8*)(lds + off);
  };

  stage(0);

  for (int t = 0; t < NT; ++t) {
    VMCNT(0);
    BARF();
    const int buf = (t & 1) * BUF;
    bf16x8 bfr[4], afr[4];
#pragma unroll
    for (int ni = 0; ni < 4; ++ni) bfr[ni] = rdB(buf, wn + ni * 16 + lr);
#pragma unroll
    for (int i = 0; i < 4; ++i) afr[i] = rdA(buf, wm + i * 16 + lr);
    if (t + 1 < NT) stage(t + 1);
    __builtin_amdgcn_s_setprio(1);
#pragma unroll
    for (int i = 0; i < 4; ++i)
#pragma unroll
      for (int ni = 0; ni < 4; ++ni)
        acc[i][ni] = __builtin_amdgcn_mfma_f32_16x16x32_bf16(afr[i], bfr[ni], acc[i][ni], 0, 0, 0);
    __builtin_amdgcn_s_setprio(0);
  }

  float bv[4];
#pragma unroll
  for (int ni = 0; ni < 4; ++ni) bv[ni] = bias[bn + wn + ni * 16 + lr];
#pragma unroll
  for (int mi = 0; mi < 4; ++mi) {
#pragma unroll
    for (int j = 0; j < 4; ++j) {
      const int rowg = bm + wm + mi * 16 + hi * 4 + j;
      float sc = 0.f;
      if constexpr (EPI == EPI_OUT_W || EPI == EPI_OUT_A)
        sc = scale[(size_t)rowg * sstride];
#pragma unroll
      for (int ni = 0; ni < 4; ++ni) {
        const int colg = bn + wn + ni * 16 + lr;
        float v = acc[mi][ni][j] + bv[ni];
        if constexpr (EPI == EPI_BF16) {
          Cb[(size_t)rowg * N + colg] = (bf16_t)v;
        } else if constexpr (EPI == EPI_OUT_W) {
          Cf[(size_t)rowg * N + colg] = sc * v;
        } else if constexpr (EPI == EPI_OUT_A) {
          Cf[(size_t)rowg * N + colg] += sc * v;
        } else {
          float bb = (float)aux[(size_t)rowg * ldaux + colg];
          float s = v / (1.f + __expf(-v));
          Cb[(size_t)rowg * N + colg] = (bf16_t)(s * bb);
        }
      }
    }
  }
}

// =======================================================================
// Causal-conv GEMM, no im2col: C[8192,1024] = A2 @ Wc^T where
// A2[t][k*1024+si] = h[t-3+k][si]. For K-tile t: k = t>>5 (row shift),
// si = (t&31)*32. OOB lanes (token's first 3 rows) load from a zero page
// (global src of global_load_lds is per-lane). Upper-half rows never cross
// a batch boundary (tiles 128-aligned, TSEQ%128==0). B = wconv [1024][4096].
// =======================================================================
__global__ __launch_bounds__(256) void k_gemm_conv(
    const bf16_t* __restrict__ h, const bf16_t* __restrict__ Bw,
    bf16_t* __restrict__ Cb, const float* __restrict__ bias,
    const bf16_t* __restrict__ zpad) {
  constexpr int N = SDIM;
  constexpr int K = SDIM * 4;
  constexpr int BUF = 16384;
  __shared__ __align__(16) char lds[2 * BUF];

  const int tid = threadIdx.x;
  const int lane = tid & 63;
  const int wave = tid >> 6;
  const int lr = lane & 15;
  const int hi = lane >> 4;

  int bx, by;
  blockmap(K, bx, by);

  const int bm = by * 128;
  const int bn = bx * 128;
  const int wm = (wave >> 1) * 64;
  const int wn = (wave & 1) * 64;

  const int srow = tid >> 2;
  const int scol = 8 * ((tid & 3) ^ ((tid >> 3) & 3));
  const int row0 = bm + srow;
  const int tt0 = row0 & (TSEQ - 1);
  const bf16_t* Bsrc = Bw + (size_t)(bn + srow) * K + scol;
  const size_t r64K = (size_t)64 * K;
  const int NT = K >> 5;

  f32x4 acc[4][4];
#pragma unroll
  for (int a = 0; a < 4; ++a)
#pragma unroll
    for (int b = 0; b < 4; ++b)
#pragma unroll
      for (int j = 0; j < 4; ++j) acc[a][b][j] = 0.f;

  auto stage = [&](int t) {
    char* l = lds + (t & 1) * BUF + tid * 16;
    const int k = t >> 5;
    const int si = (t & 31) * 32 + scol;
    const bf16_t* ga0 = (tt0 + k >= 3)
        ? h + (size_t)(row0 + k - 3) * SDIM + si : zpad;
    const bf16_t* ga1 = h + (size_t)(row0 + 64 + k - 3) * SDIM + si;
    gload16(ga0, (bf16_t*)l);
    gload16(ga1, (bf16_t*)(l + 4096));
    const bf16_t* gb = Bsrc + (size_t)t * 32;
    gload16(gb, (bf16_t*)(l + 8192));
    gload16(gb + r64K, (bf16_t*)(l + 12288));
  };
  auto rdA = [&](int buf, int row) -> bf16x8 {
    int off = buf + (row << 6) + ((hi ^ ((row >> 1) & 3)) << 4);
    return *(const bf16x8*)(lds + off);
  };
  auto rdB = [&](int buf, int row) -> bf16x8 {
    int off = buf + 8192 + (row << 6) + ((hi ^ ((row >> 1) & 3)) << 4);
    return *(const bf16x8*)(lds + off);
  };

  stage(0);

  for (int t = 0; t < NT; ++t) {
    VMCNT(0);
    BARF();
    const int buf = (t & 1) * BUF;
    bf16x8 bfr[4], afr[4];
#pragma unroll
    for (int ni = 0; ni < 4; ++ni) bfr[ni] = rdB(buf, wn + ni * 16 + lr);
#pragma unroll
    for (int i = 0; i < 4; ++i) afr[i] = rdA(buf, wm + i * 16 + lr);
    if (t + 1 < NT) stage(t + 1);
    __builtin_amdgcn_s_setprio(1);
#pragma unroll
    for (int i = 0; i < 4; ++i)
#pragma unroll
      for (int ni = 0; ni < 4; ++ni)
        acc[i][ni] = __builtin_amdgcn_mfma_f32_16x16x32_bf16(afr[i], bfr[ni], acc[i][ni], 0, 0, 0);
    __builtin_amdgcn_s_setprio(0);
  }

  float bv[4];
#pragma unroll
  for (int ni = 0; ni < 4; ++ni) bv[ni] = bias[bn + wn + ni * 16 + lr];
#pragma unroll
  for (int mi = 0; mi < 4; ++mi) {
#pragma unroll
    for (int j = 0; j < 4; ++j) {
      const int rowg = bm + wm + mi * 16 + hi * 4 + j;
#pragma unroll
      for (int ni = 0; ni < 4; ++ni) {
        const int colg = bn + wn + ni * 16 + lr;
        Cb[(size_t)rowg * N + colg] = (bf16_t)(acc[mi][ni][j] + bv[ni]);
      }
    }
  }
}

// =======================================================================
// Sparse MoE GEMM: same 128x128 4-wave core; A rows gathered via idx[]
// (GA, fc1) or slot-linear (fc2). fc2 writes plain bf16 slot rows (eo);
// combination happens in k_combine (no atomics).
// =======================================================================
template <int EPI, bool GA>
__global__ __launch_bounds__(256) void k_moe_gemm(
    const bf16_t* __restrict__ A, const bf16_t* __restrict__ Bw, size_t zB, int boff,
    bf16_t* __restrict__ Cb,
    const float* __restrict__ bias, int bstride,
    const bf16_t* __restrict__ aux,
    const int* __restrict__ ntiles_p, const int* __restrict__ tile_e,
    const int* __restrict__ tile_row, const int* __restrict__ idx,
    int N, int K) {
  constexpr int BUF = 16384;
  __shared__ __align__(16) char lds[2 * BUF];

  const int tid = threadIdx.x;
  const int lane = tid & 63;
  const int wave = tid >> 6;
  const int lr = lane & 15;
  const int hi = lane >> 4;

  const int nbx = gridDim.x, nby = gridDim.y;
  int id = blockIdx.x + nbx * blockIdx.y;
  const int nwg = nbx * nby;
  if ((nwg & 7) == 0) id = (id & 7) * (nwg >> 3) + (id >> 3);
  const int bx = id % nbx;
  const int by = id / nbx;

  const int ntiles = *ntiles_p;
  if (bx >= ntiles) return;
  const int e = tile_e[bx];
  const int bm = tile_row[bx];
  const int bn = by * 128;
  const int wm = (wave >> 1) * 64;
  const int wn = (wave & 1) * 64;

  const int srow = tid >> 2;
  const int scol = 8 * ((tid & 3) ^ ((tid >> 3) & 3));
  const int atok0 = GA ? idx[bm + srow] : (bm + srow);
  const int atok1 = GA ? idx[bm + srow + 64] : (bm + srow + 64);
  const bf16_t* Asrc0 = A + (size_t)atok0 * K + scol;
  const bf16_t* Asrc1 = A + (size_t)atok1 * K + scol;
  const bf16_t* Bsrc = Bw + (size_t)e * zB + (size_t)(boff + bn + srow) * K + scol;
  const size_t r64K = (size_t)64 * K;
  const int NT = K >> 5;

  f32x4 acc[4][4];
#pragma unroll
  for (int a = 0; a < 4; ++a)
#pragma unroll
    for (int b = 0; b < 4; ++b)
#pragma unroll
      for (int j = 0; j < 4; ++j) acc[a][b][j] = 0.f;

  auto stage = [&](int t) {
    char* l = lds + (t & 1) * BUF + tid * 16;
    gload16(Asrc0 + (size_t)t * 32, (bf16_t*)l);
    gload16(Asrc1 + (size_t)t * 32, (bf16_t*)(l + 4096));
    gload16(Bsrc + (size_t)t * 32, (bf16_t*)(l + 8192));
    gload16(Bsrc + (size_t)t * 32 + r64K, (bf16_t*)(l + 12288));
  };
  auto rdA = [&](int buf, int row) -> bf16x8 {
    int off = buf + (row << 6) + ((hi ^ ((row >> 1) & 3)) << 4);
    return *(const bf16x8*)(lds + off);
  };
  auto rdB = [&](int buf, int row) -> bf16x8 {
    int off = buf + 8192 + (row << 6) + ((hi ^ ((row >> 1) & 3)) << 4);
    return *(const bf16x8*)(lds + off);
  };

  stage(0);

  for (int t = 0; t < NT; ++t) {
    VMCNT(0);
    BARF();
    const int buf = (t & 1) * BUF;
    bf16x8 bfr[4], afr[4];
#pragma unroll
    for (int ni = 0; ni < 4; ++ni) bfr[ni] = rdB(buf, wn + ni * 16 + lr);
#pragma unroll
    for (int i = 0; i < 4; ++i) afr[i] = rdA(buf, wm + i * 16 + lr);
    if (t + 1 < NT) stage(t + 1);
    __builtin_amdgcn_s_setprio(1);
#pragma unroll
    for (int i = 0; i < 4; ++i)
#pragma unroll
      for (int ni = 0; ni < 4; ++ni)
        acc[i][ni] = __builtin_amdgcn_mfma_f32_16x16x32_bf16(afr[i], bfr[ni], acc[i][ni], 0, 0, 0);
    __builtin_amdgcn_s_setprio(0);
  }

  const float* bp = bias + (size_t)e * bstride + boff;
  float bv[4];
#pragma unroll
  for (int ni = 0; ni < 4; ++ni) bv[ni] = bp[bn + wn + ni * 16 + lr];
#pragma unroll
  for (int mi = 0; mi < 4; ++mi) {
#pragma unroll
    for (int j = 0; j < 4; ++j) {
      const int slot = bm + wm + mi * 16 + hi * 4 + j;
#pragma unroll
      for (int ni = 0; ni < 4; ++ni) {
        const int colg = bn + wn + ni * 16 + lr;
        float v = acc[mi][ni][j] + bv[ni];
        if constexpr (EPI == EPI_BF16) {
          Cb[(size_t)slot * N + colg] = (bf16_t)v;
        } else {
          float bb = (float)aux[(size_t)slot * N + colg];
          float s = v / (1.f + __expf(-v));
          Cb[(size_t)slot * N + colg] = (bf16_t)(s * bb);
        }
      }
    }
  }
}

// ---------------------------------------------------------------------------
extern "C" void kernel_launch(void* const* d_in, const int* in_sizes, int n_in,
                              void* d_out, int out_size, void* d_ws, size_t ws_size,
                              hipStream_t stream) {
  (void)in_sizes; (void)n_in; (void)out_size; (void)ws_size;
  const float* x    = (const float*)d_in[0];
  const float* rW   = (const float*)d_in[1];
  const float* rb   = (const float*)d_in[2];
  const float* d1W  = (const float*)d_in[3];
  const float* d1b  = (const float*)d_in[4];
  const float* d2W  = (const float*)d_in[5];
  const float* d2b  = (const float*)d_in[6];
  const float* sWin = (const float*)d_in[7];
  const float* sbin = (const float*)d_in[8];
  const float* sWc  = (const float*)d_in[9];
  const float* sbc  = (const float*)d_in[10];
  const float* sWo  = (const float*)d_in[11];
  const float* sbo  = (const float*)d_in[12];
  const float* mW   = (const float*)d_in[13];
  const float* mb   = (const float*)d_in[14];
  const float* eW1  = (const float*)d_in[15];
  const float* eb1  = (const float*)d_in[16];
  const float* eW2  = (const float*)d_in[17];
  const float* eb2  = (const float*)d_in[18];
  float* out = (float*)d_out;

  char* ws = (char*)d_ws;
  size_t off = 0;
  auto alloc = [&](size_t bytes) -> void* {
    void* p = ws + off;
    off += (bytes + 255) & ~(size_t)255;
    return p;
  };
  bf16_t* xb    = (bf16_t*)alloc((size_t)NTOK * DDIM * 2);
  bf16_t* wd1   = (bf16_t*)alloc((size_t)2 * HDIM * DDIM * 2);
  bf16_t* wd2   = (bf16_t*)alloc((size_t)DDIM * HDIM * 2);
  bf16_t* wsin  = (bf16_t*)alloc((size_t)SDIM * DDIM * 2);
  bf16_t* wconv = (bf16_t*)alloc((size_t)SDIM * SDIM * 4 * 2);
  bf16_t* wsout = (bf16_t*)alloc((size_t)DDIM * SDIM * 2);
  bf16_t* we1   = (bf16_t*)alloc((size_t)NEXP * 2 * HEXP * DDIM * 2);
  bf16_t* we2   = (bf16_t*)alloc((size_t)NEXP * DDIM * HEXP * 2);
  bf16_t* Cc    = (bf16_t*)alloc((size_t)NTOK * HDIM * 2);  // dense swiglu | MoE swiglu (slot)
  bf16_t* Dd    = (bf16_t*)alloc((size_t)NTOK * HDIM * 2);  // dense fc1-b | MoE fc1-b (slot) | eo
  bf16_t* th    = (bf16_t*)alloc((size_t)NTOK * SDIM * 2);
  bf16_t* tsq   = (bf16_t*)alloc((size_t)NTOK * SDIM * 2);
  float*  bw3   = (float*)alloc((size_t)NTOK * 3 * 4);
  int*    top2e = (int*)alloc((size_t)NTOK * 2 * 4);
  float*  top2w = (float*)alloc((size_t)NTOK * 2 * 4);
  int*    slotm = (int*)alloc((size_t)NTOK * 2 * 4);
  int*    cnt   = (int*)alloc(NEXP * 4);
  int*    fill  = (int*)alloc(NEXP * 4);
  int*    basep = (int*)alloc((NEXP + 1) * 4);
  int*    ntl   = (int*)alloc(4);
  int*    t_e   = (int*)alloc(MAXTILES * 4);
  int*    t_row = (int*)alloc(MAXTILES * 4);
  int*    idx   = (int*)alloc(MAXROWS * 4);
  bf16_t* zpad  = (bf16_t*)alloc(256);
  // eo aliases Dd: Dd's contents (MoE fc1-b slot rows) are dead once the MoE
  // swiglu GEMM has consumed them; fc2 then writes eo[slot][1024] here
  // (needs 35.7 MB of Dd's 67 MB). Keeps total ws at the proven ~248 MB.
  bf16_t* eo    = Dd;

  // conversions + router + MoE bookkeeping
  k_f32_to_bf16<<<4096, 256, 0, stream>>>(x, xb, NTOK * DDIM / 8);
  k_f32_to_bf16<<<4096, 256, 0, stream>>>(d1W, wd1, 2 * HDIM * DDIM / 8);
  k_f32_to_bf16<<<2048, 256, 0, stream>>>(d2W, wd2, DDIM * HDIM / 8);
  k_f32_to_bf16<<<512, 256, 0, stream>>>(sWin, wsin, SDIM * DDIM / 8);
  k_convw<<<2048, 256, 0, stream>>>(sWc, wconv);
  k_f32_to_bf16<<<512, 256, 0, stream>>>(sWo, wsout, DDIM * SDIM / 8);
  k_f32_to_bf16<<<4096, 256, 0, stream>>>(eW1, we1, NEXP * 2 * HEXP * DDIM / 8);
  k_f32_to_bf16<<<2048, 256, 0, stream>>>(eW2, we2, NEXP * DDIM * HEXP / 8);
  k_zero<<<(MAXROWS + 255) / 256, 256, 0, stream>>>(cnt, fill, idx, zpad);
  k_router<<<2048, 256, 0, stream>>>(x, rW, rb, mW, mb, bw3, top2e, top2w);
  k_count<<<1, 1024, 0, stream>>>(top2e, cnt);
  k_scan<<<1, 64, 0, stream>>>(cnt, basep, ntl, t_e, t_row);
  k_scatter<<<NTOK / 256, 256, 0, stream>>>(top2e, top2w, basep, fill, idx, slotm);

  // ---- dense branch: fc1-b, fc1-a(+fused swiglu), d2 -> out ('=') ----
  k_gemm<EPI_BF16><<<dim3(32, 64), 256, 0, stream>>>(
      xb, wd1 + (size_t)HDIM * DDIM, Dd, nullptr, d1b + HDIM, nullptr, 0, nullptr, 0,
      HDIM, DDIM);
  k_gemm<EPI_SWIG><<<dim3(32, 64), 256, 0, stream>>>(
      xb, wd1, Cc, nullptr, d1b, nullptr, 0, Dd, HDIM, HDIM, DDIM);
  k_gemm<EPI_OUT_W><<<dim3(8, 64), 256, 0, stream>>>(
      Cc, wd2, nullptr, out, d2b, bw3, 3, nullptr, 0, DDIM, HDIM);

  // ---- sparse MoE: gathered fc1-b, fc1-a(+swiglu), fc2 -> eo, combine ----
  k_moe_gemm<EPI_BF16, true><<<dim3(MAXTILES, 4), 256, 0, stream>>>(
      xb, we1, (size_t)2 * HEXP * DDIM, HEXP, Dd, eb1, 2 * HEXP, nullptr,
      ntl, t_e, t_row, idx, HEXP, DDIM);
  k_moe_gemm<EPI_SWIG, true><<<dim3(MAXTILES, 4), 256, 0, stream>>>(
      xb, we1, (size_t)2 * HEXP * DDIM, 0, Cc, eb1, 2 * HEXP, Dd,
      ntl, t_e, t_row, idx, HEXP, DDIM);
  k_moe_gemm<EPI_BF16, false><<<dim3(MAXTILES, 8), 256, 0, stream>>>(
      Cc, we2, (size_t)DDIM * HEXP, 0, eo, eb2, DDIM, nullptr,
      ntl, t_e, t_row, idx, DDIM, HEXP);
  k_combine<<<NTOK / 4, 256, 0, stream>>>(eo, slotm, top2w, out);

  // ---- SSM branch (conv reads th directly, no im2col) ----
  k_gemm<EPI_BF16><<<dim3(8, 64), 256, 0, stream>>>(
      xb, wsin, th, nullptr, sbin, nullptr, 0, nullptr, 0, SDIM, DDIM);
  k_gemm_conv<<<dim3(8, 64), 256, 0, stream>>>(th, wconv, tsq, sbc, zpad);
  k_gemm<EPI_OUT_A><<<dim3(8, 64), 256, 0, stream>>>(
      tsq, wsout, nullptr, out, sbo, bw3 + 1, 3, nullptr, 0, DDIM, SDIM);
}